// Round 2
// baseline (625.871 us; speedup 1.0000x reference)
//
#include <hip/hip_runtime.h>
#include <hip/hip_bf16.h>

// Problem constants (fixed by the reference setup_inputs()).
#define J_     24
#define CIN_   32
#define COUT_  32
#define KW_    3
#define B_     8
#define T_     4096
#define R_     12
#define NEG_SLOPE_ 0.2f
#define TT_    256           // t-tile per block
#define POOLED_SZ_ (B_ * R_ * COUT_ * T_)   // 12,582,912

// Adjacency bitmasks: ADJMASK[i] has bit n set iff n in ADJ_LIST[i].
__device__ __constant__ unsigned int ADJMASK[J_] = {
    0x0000000Fu, // 0: {0,1,2,3}
    0x00000013u, // 1: {1,0,4}
    0x00000025u, // 2: {2,0,5}
    0x00000049u, // 3: {3,0,6}
    0x00000092u, // 4: {4,1,7}
    0x00000124u, // 5: {5,2,8}
    0x00000248u, // 6: {6,3,9}
    0x00000490u, // 7: {7,4,10}
    0x00000920u, // 8: {8,5,11}
    0x00007240u, // 9: {9,6,12,13,14}
    0x00000480u, // 10: {10,7}
    0x00000900u, // 11: {11,8}
    0x00009200u, // 12: {12,9,15}
    0x00012200u, // 13: {13,9,16}
    0x00024200u, // 14: {14,9,17}
    0x00009000u, // 15: {15,12}
    0x00052000u, // 16: {16,13,18}
    0x000A4000u, // 17: {17,14,19}  ** FIXED: was 0x94000 (bits 19,16,14) **
    0x00150000u, // 18: {18,16,20}
    0x002A0000u, // 19: {19,17,21}
    0x00540000u, // 20: {20,18,22}
    0x00A80000u, // 21: {21,19,23}
    0x00500000u, // 22: {22,20}
    0x00A00000u  // 23: {23,21}
};

// ---------------------------------------------------------------------------
// Main fused kernel: masked conv1d(K=3,SAME) + bias + leakyReLU + pair-mean.
// Block = (b, region r, t-tile). 256 threads, thread t owns one time index and
// 64 accumulators (32 cout for each of the region's two joints).
// ---------------------------------------------------------------------------
__global__ __launch_bounds__(256)
void skel_main(const float* __restrict__ x, const float* __restrict__ W,
               const float* __restrict__ bias, float* __restrict__ out)
{
    const int tid = threadIdx.x;
    const int t0  = blockIdx.x * TT_;
    const int r   = blockIdx.y;
    const int b   = blockIdx.z;
    const int j0  = 2 * r;
    const int j1  = 2 * r + 1;
    const unsigned m0 = ADJMASK[j0];
    const unsigned m1 = ADJMASK[j1];
    const unsigned mu = m0 | m1;

    __shared__ float xs[CIN_][TT_ + 2];

    float acc0[COUT_];
    float acc1[COUT_];
#pragma unroll
    for (int i = 0; i < COUT_; ++i) { acc0[i] = 0.0f; acc1[i] = 0.0f; }

    const float* xb = x + (size_t)b * (J_ * CIN_) * T_;
    const int WROW = J_ * CIN_ * KW_;   // 2304: stride between output channels

    for (int nb = 0; nb < J_; ++nb) {
        if (!((mu >> nb) & 1u)) continue;           // uniform branch per block

        __syncthreads();                            // protect prior-iter reads
        // Stage x[b, nb*32 + ci, t0-1 .. t0+TT] into LDS (zero-pad at edges).
        for (int idx = tid; idx < CIN_ * (TT_ + 2); idx += 256) {
            const int ci = idx / (TT_ + 2);
            const int tt = idx - ci * (TT_ + 2);
            const int t  = t0 - 1 + tt;
            float v = 0.0f;
            if (t >= 0 && t < T_)
                v = xb[(size_t)(nb * CIN_ + ci) * T_ + t];
            xs[ci][tt] = v;
        }
        __syncthreads();

        const bool w0 = (m0 >> nb) & 1u;
        const bool w1 = (m1 >> nb) & 1u;
        const float* Wp0 = W + (size_t)(j0 * COUT_) * WROW + (size_t)nb * CIN_ * KW_;
        const float* Wp1 = W + (size_t)(j1 * COUT_) * WROW + (size_t)nb * CIN_ * KW_;

        for (int cb = 0; cb < CIN_; cb += 8) {
            float xv[8][3];
#pragma unroll
            for (int q = 0; q < 8; ++q) {
                xv[q][0] = xs[cb + q][tid];
                xv[q][1] = xs[cb + q][tid + 1];
                xv[q][2] = xs[cb + q][tid + 2];
            }
            if (w0) {
#pragma unroll
                for (int co = 0; co < COUT_; ++co) {
                    const float* wr = Wp0 + (size_t)co * WROW + cb * KW_;
                    float a = acc0[co];
#pragma unroll
                    for (int q = 0; q < 8; ++q) {
                        a += xv[q][0] * wr[q * 3 + 0];
                        a += xv[q][1] * wr[q * 3 + 1];
                        a += xv[q][2] * wr[q * 3 + 2];
                    }
                    acc0[co] = a;
                }
            }
            if (w1) {
#pragma unroll
                for (int co = 0; co < COUT_; ++co) {
                    const float* wr = Wp1 + (size_t)co * WROW + cb * KW_;
                    float a = acc1[co];
#pragma unroll
                    for (int q = 0; q < 8; ++q) {
                        a += xv[q][0] * wr[q * 3 + 0];
                        a += xv[q][1] * wr[q * 3 + 1];
                        a += xv[q][2] * wr[q * 3 + 2];
                    }
                    acc1[co] = a;
                }
            }
        }
    }

    // Epilogue: bias + leaky ReLU + pair mean, coalesced stores.
    float* ob = out + ((size_t)b * (R_ * COUT_) + (size_t)r * COUT_) * T_ + t0 + tid;
#pragma unroll
    for (int co = 0; co < COUT_; ++co) {
        float y0 = acc0[co] + bias[j0 * COUT_ + co];
        y0 = (y0 > 0.0f) ? y0 : NEG_SLOPE_ * y0;
        float y1 = acc1[co] + bias[j1 * COUT_ + co];
        y1 = (y1 > 0.0f) ? y1 : NEG_SLOPE_ * y1;
        ob[(size_t)co * T_] = 0.5f * (y0 + y1);
    }
}

// ---------------------------------------------------------------------------
// Aux kernel: emit REGIONS (0..23) and POST_ADJ (region-level adjacency),
// both compile-time constants, as float32 into the tail of d_out.
// ---------------------------------------------------------------------------
__global__ void skel_aux(float* __restrict__ out_regions, float* __restrict__ out_post)
{
    const int i = threadIdx.x;
    if (i < J_) out_regions[i] = (float)i;
    if (i < R_ * R_) {
        const int r1 = i / R_;
        const int r2 = i - r1 * R_;
        const unsigned m = ADJMASK[2 * r1] | ADJMASK[2 * r1 + 1];
        out_post[i] = ((m >> (2 * r2)) & 3u) ? 1.0f : 0.0f;
    }
}

extern "C" void kernel_launch(void* const* d_in, const int* in_sizes, int n_in,
                              void* d_out, int out_size, void* d_ws, size_t ws_size,
                              hipStream_t stream)
{
    const float* x    = (const float*)d_in[0];
    const float* W    = (const float*)d_in[1];
    const float* bias = (const float*)d_in[2];
    float* out = (float*)d_out;

    dim3 grid(T_ / TT_, R_, B_);
    skel_main<<<grid, 256, 0, stream>>>(x, W, bias, out);

    float* out_regions = out + POOLED_SZ_;
    float* out_post    = out_regions + (J_);   // 24 REGIONS entries, then 144 POST_ADJ
    skel_aux<<<1, 256, 0, stream>>>(out_regions, out_post);
}

// Round 5
// 112.756 us; speedup vs baseline: 5.5507x; 5.5507x over previous
//
#include <hip/hip_runtime.h>
#include <hip/hip_bf16.h>

// Problem constants (fixed by the reference setup_inputs()).
#define J_     24
#define CIN_   32
#define COUT_  32
#define B_     8
#define T_     4096
#define R_     12
#define TT_    128                         // t per main-kernel block
#define POOLED_SZ_ (B_ * R_ * COUT_ * T_)  // 12,582,912
#define XT_ELEMS_  ((size_t)B_ * T_ * (J_ * CIN_))   // 25,165,824 bf16
#define NFRAG_     420                     // 70 edges * 3 kw * 2 co-tiles

typedef float  f32x4  __attribute__((ext_vector_type(4)));
typedef short  bf16x8 __attribute__((ext_vector_type(8)));
typedef unsigned short us8 __attribute__((ext_vector_type(8)));

// Adjacency bitmasks: ADJMASK[i] has bit n set iff n in ADJ_LIST[i].
__device__ __constant__ unsigned int ADJMASK[J_] = {
    0x0000000Fu, 0x00000013u, 0x00000025u, 0x00000049u, 0x00000092u, 0x00000124u,
    0x00000248u, 0x00000490u, 0x00000920u, 0x00007240u, 0x00000480u, 0x00000900u,
    0x00009200u, 0x00012200u, 0x00024200u, 0x00009000u, 0x00052000u, 0x000A4000u,
    0x00150000u, 0x002A0000u, 0x00540000u, 0x00A80000u, 0x00500000u, 0x00A00000u
};
// Flat adjacency, ASCENDING per joint (matches ascending-bit iteration in main).
__device__ __constant__ int ADJ_FLAT[70] = {
    0,1,2,3,  0,1,4,  0,2,5,  0,3,6,  1,4,7,  2,5,8,  3,6,9,  4,7,10,  5,8,11,
    6,9,12,13,14,  7,10,  8,11,  9,12,15,  9,13,16,  9,14,17,  12,15,
    13,16,18,  14,17,19,  16,18,20,  17,19,21,  18,20,22,  19,21,23,  20,22,  21,23
};
__device__ __constant__ int ADJ_OFF[J_ + 1] = {
    0,4,7,10,13,16,19,22,25,28,33,35,37,40,43,46,48,51,54,57,60,63,66,68,70
};

static __device__ __forceinline__ unsigned short f2bf(float f) {
    unsigned u = __float_as_uint(f);
    unsigned r = (u + 0x7fffu + ((u >> 16) & 1u)) >> 16;   // RNE
    return (unsigned short)r;
}

// ---------------------------------------------------------------------------
// Pre-kernel 1: x fp32 [b][768][4096] -> xT bf16 [b][4096][768] via LDS tiles.
// ---------------------------------------------------------------------------
__global__ __launch_bounds__(256)
void skel_transpose(const float* __restrict__ x, unsigned short* __restrict__ xT)
{
    __shared__ float xs[32][257];
    const int tid = threadIdx.x;
    const int tt0 = blockIdx.x * 256;   // t tile
    const int cg  = blockIdx.y;         // channel group of 32 (0..23)
    const int b   = blockIdx.z;

    const float* xp = x + ((size_t)b * (J_ * CIN_) + cg * 32) * T_ + tt0;
#pragma unroll
    for (int i = 0; i < 8; ++i) {
        const int idx = tid + i * 256;
        const int row = idx >> 6;            // 0..31
        const int c4  = (idx & 63) << 2;     // 0..252
        const float4 v = *(const float4*)(xp + (size_t)row * T_ + c4);
        xs[row][c4 + 0] = v.x; xs[row][c4 + 1] = v.y;
        xs[row][c4 + 2] = v.z; xs[row][c4 + 3] = v.w;
    }
    __syncthreads();

    union { unsigned short u[32]; uint4 q[4]; } pk;
#pragma unroll
    for (int c = 0; c < 32; ++c) pk.u[c] = f2bf(xs[c][tid]);
    unsigned short* dst = xT + ((size_t)b * T_ + tt0 + tid) * (J_ * CIN_) + cg * 32;
#pragma unroll
    for (int k = 0; k < 4; ++k) *(uint4*)(dst + k * 8) = pk.q[k];
}

// ---------------------------------------------------------------------------
// Pre-kernel 2: pack masked W blocks into per-lane MFMA A-fragments (bf16),
// k-slot map identical to the B side: ci = (lane>>4)*8 + elem. Block 420
// additionally writes the REGIONS / POST_ADJ constant outputs.
// ---------------------------------------------------------------------------
__global__ __launch_bounds__(64)
void skel_pack(const float* __restrict__ W, unsigned short* __restrict__ wsW,
               float* __restrict__ out_regions, float* __restrict__ out_post)
{
    const int fb = blockIdx.x;
    const int l  = threadIdx.x;          // 0..63
    if (fb == NFRAG_) {
        for (int i = l; i < J_; i += 64) out_regions[i] = (float)i;
        for (int i = l; i < R_ * R_; i += 64) {
            const int r1 = i / R_, r2 = i - r1 * R_;
            const unsigned m = ADJMASK[2 * r1] | ADJMASK[2 * r1 + 1];
            out_post[i] = ((m >> (2 * r2)) & 3u) ? 1.0f : 0.0f;
        }
        return;
    }
    const int cot = fb & 1;
    const int tmp = fb >> 1;
    const int kw  = tmp % 3;
    const int e   = tmp / 3;             // 0..69 flat edge index
    int jout = 0;
    while (ADJ_OFF[jout + 1] <= e) ++jout;
    const int nb = ADJ_FLAT[e];
    const int co = cot * 16 + (l & 15);
    const int hi = l >> 4;

    union { unsigned short u[8]; uint4 q; } pk;
#pragma unroll
    for (int j = 0; j < 8; ++j) {
        const int ci = hi * 8 + j;
        const float w = W[((size_t)(jout * COUT_ + co) * (J_ * CIN_) + (nb * CIN_ + ci)) * 3 + kw];
        pk.u[j] = f2bf(w);
    }
    *(uint4*)(wsW + (size_t)fb * 512 + l * 8) = pk.q;
}

// ---------------------------------------------------------------------------
// Main kernel: MFMA conv + bias + leakyReLU + pair-mean. No LDS, no barriers.
// 1D grid 3072, XCD-chunked swizzle: all 12 regions of one (b,t-tile) land on
// the same XCD so shared xT rows stay L2-resident.
// ---------------------------------------------------------------------------
__global__ __launch_bounds__(256)
void skel_main(const unsigned short* __restrict__ xT,
               const unsigned short* __restrict__ wsW,
               const float* __restrict__ bias, float* __restrict__ out)
{
    // Block decode with XCD swizzle (8 XCDs; dispatch round-robins blockIdx%8).
    const int i    = blockIdx.x;          // 0..3071
    const int xcd  = i & 7;
    const int slot = i >> 3;              // 0..383
    const int r    = slot % R_;
    const int gi   = slot / R_;           // 0..31
    const int g    = xcd + 8 * gi;        // (b,t-tile) group 0..255
    const int b    = g >> 5;
    const int t0   = (g & 31) * TT_;

    const int tid  = threadIdx.x;
    const int wv   = tid >> 6;
    const int lane = tid & 63;
    const int l15  = lane & 15;
    const int hi   = lane >> 4;
    const int s0   = wv * 2;              // this wave's two 16-wide t subtiles

    const int j0 = 2 * r, j1 = 2 * r + 1;
    const unsigned m0 = ADJMASK[j0], m1 = ADJMASK[j1];

    f32x4 acc[2][2][2];                   // [joint][co_tile][subtile]
#pragma unroll
    for (int a = 0; a < 2; ++a)
#pragma unroll
        for (int c = 0; c < 2; ++c)
#pragma unroll
            for (int s = 0; s < 2; ++s) acc[a][c][s] = (f32x4){0.f, 0.f, 0.f, 0.f};

    const unsigned short* xTb = xT + (size_t)b * T_ * (J_ * CIN_) + hi * 8;
    const int base0 = ADJ_OFF[j0], base1 = ADJ_OFF[j1];
    int n0 = 0, n1 = 0;

    for (int nb = 0; nb < J_; ++nb) {
        const int e0 = (m0 >> nb) & 1, e1 = (m1 >> nb) & 1;
        if (!(e0 | e1)) continue;
        const unsigned short* xcol = xTb + nb * CIN_;

        // B fragments: 3 kw shifts x 2 subtiles, 16B/lane each.
        bf16x8 bfr[3][2];
#pragma unroll
        for (int kw = 0; kw < 3; ++kw) {
#pragma unroll
            for (int sl = 0; sl < 2; ++sl) {
                const int t  = t0 + (s0 + sl) * 16 + l15 + kw - 1;
                const int tc = t < 0 ? 0 : (t > T_ - 1 ? T_ - 1 : t);
                us8 v = *(const us8*)(xcol + (size_t)tc * (J_ * CIN_));
                if ((unsigned)t >= (unsigned)T_) {
                    const us8 z = {0, 0, 0, 0, 0, 0, 0, 0};
                    v = z;
                }
                bfr[kw][sl] = (bf16x8)v;
            }
        }
        if (e0) {
            const unsigned short* fp = wsW + (size_t)(base0 + n0) * 6 * 512 + lane * 8;
#pragma unroll
            for (int kw = 0; kw < 3; ++kw)
#pragma unroll
                for (int cot = 0; cot < 2; ++cot) {
                    const bf16x8 a = *(const bf16x8*)(fp + (kw * 2 + cot) * 512);
#pragma unroll
                    for (int sl = 0; sl < 2; ++sl)
                        acc[0][cot][sl] = __builtin_amdgcn_mfma_f32_16x16x32_bf16(
                            a, bfr[kw][sl], acc[0][cot][sl], 0, 0, 0);
                }
            ++n0;
        }
        if (e1) {
            const unsigned short* fp = wsW + (size_t)(base1 + n1) * 6 * 512 + lane * 8;
#pragma unroll
            for (int kw = 0; kw < 3; ++kw)
#pragma unroll
                for (int cot = 0; cot < 2; ++cot) {
                    const bf16x8 a = *(const bf16x8*)(fp + (kw * 2 + cot) * 512);
#pragma unroll
                    for (int sl = 0; sl < 2; ++sl)
                        acc[1][cot][sl] = __builtin_amdgcn_mfma_f32_16x16x32_bf16(
                            a, bfr[kw][sl], acc[1][cot][sl], 0, 0, 0);
                }
            ++n1;
        }
    }

    // Epilogue: bias + leakyReLU + pair mean. D layout: col=lane&15 (t),
    // row=(lane>>4)*4+q (co within 16-tile). [verified m89]
#pragma unroll
    for (int cot = 0; cot < 2; ++cot) {
#pragma unroll
        for (int sl = 0; sl < 2; ++sl) {
#pragma unroll
            for (int q = 0; q < 4; ++q) {
                const int co = cot * 16 + hi * 4 + q;
                float y0 = acc[0][cot][sl][q] + bias[j0 * COUT_ + co];
                y0 = (y0 > 0.f) ? y0 : 0.2f * y0;
                float y1 = acc[1][cot][sl][q] + bias[j1 * COUT_ + co];
                y1 = (y1 > 0.f) ? y1 : 0.2f * y1;
                out[((size_t)b * (R_ * COUT_) + r * COUT_ + co) * T_
                    + t0 + (s0 + sl) * 16 + l15] = 0.5f * (y0 + y1);
            }
        }
    }
}

extern "C" void kernel_launch(void* const* d_in, const int* in_sizes, int n_in,
                              void* d_out, int out_size, void* d_ws, size_t ws_size,
                              hipStream_t stream)
{
    const float* x    = (const float*)d_in[0];
    const float* W    = (const float*)d_in[1];
    const float* bias = (const float*)d_in[2];
    float* out = (float*)d_out;

    unsigned short* xT  = (unsigned short*)d_ws;                 // 48 MiB bf16
    unsigned short* wsW = xT + XT_ELEMS_;                        // +420 KiB frags

    dim3 tgrid(T_ / 256, J_ * CIN_ / 32, B_);
    skel_transpose<<<tgrid, 256, 0, stream>>>(x, xT);

    float* out_regions = out + POOLED_SZ_;
    float* out_post    = out_regions + J_;
    skel_pack<<<NFRAG_ + 1, 64, 0, stream>>>(W, wsW, out_regions, out_post);

    skel_main<<<(T_ / TT_) * R_ * B_, 256, 0, stream>>>(xT, wsW, bias, out);
}